// Round 5
// baseline (424.657 us; speedup 1.0000x reference)
//
#include <hip/hip_runtime.h>
#include <math.h>

// Problem constants (fixed by reference):
// B=2, L=2048, D=2048, H=16, G=4, HD=128, EPS=1e-6, scale = 1/HD^2 = 1/16384
#define SEQ 2048
#define DMODEL 2048
#define NHQ 16
#define NHK 4

typedef __attribute__((ext_vector_type(8))) short short8;
typedef __attribute__((ext_vector_type(4))) float floatx4;

__device__ __forceinline__ unsigned short f2bf(float f) {
  unsigned int u = __builtin_bit_cast(unsigned int, f);
  u += 0x7fffu + ((u >> 16) & 1u);   // round-to-nearest-even
  return (unsigned short)(u >> 16);
}

// ---------------------------------------------------------------------------
// cast fp32 -> bf16, 4 elements/thread.
// ---------------------------------------------------------------------------
__global__ __launch_bounds__(256) void cast_bf16(const float* __restrict__ in,
                                                 unsigned short* __restrict__ out) {
  const size_t i = ((size_t)blockIdx.x * 256 + threadIdx.x) * 4;
  const float4 v = *(const float4*)(in + i);
  ushort4 w;
  w.x = f2bf(v.x); w.y = f2bf(v.y); w.z = f2bf(v.z); w.w = f2bf(v.w);
  *(ushort4*)(out + i) = w;
}

// ---------------------------------------------------------------------------
// transpose + cast: in fp32 [R][C] -> out bf16 [C][R]. 32x32 LDS tile.
// ---------------------------------------------------------------------------
__global__ __launch_bounds__(256) void transpose_cast(const float* __restrict__ in,
                                                      unsigned short* __restrict__ out,
                                                      int R, int C) {
  __shared__ float tile[32][33];
  const int tx = threadIdx.x, ty = threadIdx.y;
  const int c0 = blockIdx.x * 32, r0 = blockIdx.y * 32;
#pragma unroll
  for (int j = 0; j < 4; ++j)
    tile[ty + j * 8][tx] = in[(size_t)(r0 + ty + j * 8) * C + c0 + tx];
  __syncthreads();
#pragma unroll
  for (int j = 0; j < 4; ++j)
    out[(size_t)(c0 + ty + j * 8) * R + r0 + tx] = f2bf(tile[tx][ty + j * 8]);
}

// ---------------------------------------------------------------------------
// V transpose from fused qkv buffer: qkv fp32 [b*L][3072] (V at 2560+g*128+d)
// -> vt bf16 [(b*G+g)][128][L]. block (32,8), grid (L/32, 128/32, B*G).
// ---------------------------------------------------------------------------
__global__ __launch_bounds__(256) void transpose_v(const float* __restrict__ in,
                                                   unsigned short* __restrict__ out) {
  __shared__ float tile[32][33];
  const int tx = threadIdx.x, ty = threadIdx.y;
  const int l0 = blockIdx.x * 32, d0 = blockIdx.y * 32;
  const int bg = blockIdx.z;                 // b*4+g
  const int b = bg >> 2, g = bg & 3;
#pragma unroll
  for (int j = 0; j < 4; ++j)
    tile[ty + j * 8][tx] = in[(size_t)(b * SEQ + l0 + ty + j * 8) * 3072 + 2560 + g * 128 + d0 + tx];
  __syncthreads();
#pragma unroll
  for (int j = 0; j < 4; ++j)
    out[((size_t)bg * 128 + d0 + ty + j * 8) * SEQ + l0 + tx] = f2bf(tile[tx][ty + j * 8]);
}

// ---------------------------------------------------------------------------
// bf16 MFMA GEMM (m97 structure): C[M][N] = A[M][K] @ B[K][N], fp32 out.
// ---------------------------------------------------------------------------
__global__ __launch_bounds__(256) void gemm_bf16(const unsigned short* __restrict__ A,
                                                 const unsigned short* __restrict__ Bt,
                                                 float* __restrict__ C,
                                                 int M, int N, int K) {
  __shared__ unsigned short As[128 * 32];
  __shared__ unsigned short Bs[128 * 32];
  const int tid = threadIdx.x;
  const int wave = tid >> 6;
  const int lane = tid & 63;
  const int bm = blockIdx.y * 128;
  const int bn = blockIdx.x * 128;
  const int wr = wave >> 1;
  const int wc = wave & 1;
  const int m15 = lane & 15;
  const int quad = lane >> 4;

  floatx4 acc[4][4];
#pragma unroll
  for (int i = 0; i < 4; ++i)
#pragma unroll
    for (int j = 0; j < 4; ++j) acc[i][j] = (floatx4){0.f, 0.f, 0.f, 0.f};

  const int srow = lane >> 2;
  const int scol = (lane & 3) * 8;

  for (int k0 = 0; k0 < K; k0 += 32) {
#pragma unroll
    for (int it = 0; it < 2; ++it) {
      const int rowa = wave * 32 + it * 16;
      const unsigned short* ga = A + (size_t)(bm + rowa + srow) * K + k0 + scol;
      const unsigned short* gb = Bt + (size_t)(bn + rowa + srow) * K + k0 + scol;
      __builtin_amdgcn_global_load_lds(
          (const __attribute__((address_space(1))) void*)ga,
          (__attribute__((address_space(3))) void*)&As[rowa * 32], 16, 0, 0);
      __builtin_amdgcn_global_load_lds(
          (const __attribute__((address_space(1))) void*)gb,
          (__attribute__((address_space(3))) void*)&Bs[rowa * 32], 16, 0, 0);
    }
    __syncthreads();

    short8 af[4], bfr[4];
    const unsigned short* pa = &As[(wr * 64 + m15) * 32 + quad * 8];
    const unsigned short* pb = &Bs[(wc * 64 + m15) * 32 + quad * 8];
#pragma unroll
    for (int i = 0; i < 4; ++i) af[i] = *(const short8*)(pa + i * 16 * 32);
#pragma unroll
    for (int j = 0; j < 4; ++j) bfr[j] = *(const short8*)(pb + j * 16 * 32);
#pragma unroll
    for (int i = 0; i < 4; ++i)
#pragma unroll
      for (int j = 0; j < 4; ++j)
        acc[i][j] = __builtin_amdgcn_mfma_f32_16x16x32_bf16(af[i], bfr[j], acc[i][j], 0, 0, 0);
    __syncthreads();
  }

#pragma unroll
  for (int i = 0; i < 4; ++i)
#pragma unroll
    for (int j = 0; j < 4; ++j) {
      const int col = bn + wc * 64 + j * 16 + m15;
#pragma unroll
      for (int reg = 0; reg < 4; ++reg) {
        const int row = bm + wr * 64 + i * 16 + quad * 4 + reg;
        C[(size_t)row * N + col] = acc[i][j][reg];
      }
    }
}

// ---------------------------------------------------------------------------
// Fused RMSNorm + RoPE: fp32 in at in[row*rowStride + colOff + head*128 + d]
// -> bf16 out [(b*NH+h)][l][128].
// ---------------------------------------------------------------------------
__global__ __launch_bounds__(256) void rmsnorm_rope(const float* __restrict__ in,
                                                    unsigned short* __restrict__ out,
                                                    int rowStride, int colOff, int NH,
                                                    const float* __restrict__ scale,
                                                    const float* __restrict__ cosb,
                                                    const float* __restrict__ sinb) {
  const int t = threadIdx.x;                       // 0..63
  const int head = blockIdx.y * 4 + threadIdx.y;
  const int row = blockIdx.x;                      // 0..B*L-1
  const int b = row >> 11;
  const int l = row & (SEQ - 1);
  const float* base = in + (size_t)row * rowStride + colOff + head * 128;
  float v0 = base[t];
  float v1 = base[t + 64];
  float ss = v0 * v0 + v1 * v1;
#pragma unroll
  for (int m = 1; m < 64; m <<= 1) ss += __shfl_xor(ss, m);
  const float r = rsqrtf(ss * (1.0f / 128.0f) + 1e-6f);
  const float a0 = v0 * r * scale[t];
  const float a1 = v1 * r * scale[t + 64];
  const float c0 = cosb[(size_t)l * 128 + t];
  const float s0 = sinb[(size_t)l * 128 + t];
  const float c1 = cosb[(size_t)l * 128 + t + 64];
  const float s1 = sinb[(size_t)l * 128 + t + 64];
  unsigned short* dst = out + ((size_t)(b * NH + head) * SEQ + l) * 128;
  dst[t]      = f2bf(a0 * c0 - a1 * s0);
  dst[t + 64] = f2bf(a1 * c1 + a0 * s1);
}

// ---------------------------------------------------------------------------
// MFMA flash attention (causal GQA), no-max softmax (|s| <= 128/16384 by
// Cauchy-Schwarz on rms-normed q,k with norm-preserving RoPE, unit scales).
// BM=128: grid (B*H, L/128) reversed-y, 256 threads = 4 waves.
// Wave w owns query rows {rb*64 + w*16 + 0..15 : rb=0,1} of the 128-row tile.
// Each K/V stage feeds 2x the MFMA of the BM=64 version, and every Ks/Vs
// fragment read is shared across the two row-blocks (halved ds_read/MFMA).
// Final half-tile (keys q0+64..q0+127, rb=1 rows only) peeled out of the loop.
// LDS: Ks 16K + Vs 16K + Ps 18K = 50 KB -> 3 blocks/CU.
// ---------------------------------------------------------------------------
__global__ __launch_bounds__(256, 3) void attn_mfma(const unsigned short* __restrict__ qb,
                                                    const unsigned short* __restrict__ kb,
                                                    const unsigned short* __restrict__ vtb,
                                                    unsigned short* __restrict__ o) {
  __shared__ unsigned short Ks[64 * 128];
  __shared__ unsigned short Vs[128 * 64];
  __shared__ unsigned short Ps[128 * 72];

  const int tid = threadIdx.x;
  const int wave = tid >> 6;
  const int lane = tid & 63;
  const int m15 = lane & 15;
  const int quad = lane >> 4;
  const int bh = blockIdx.x;           // 0..31
  const int b = bh >> 4;
  const int h = bh & 15;
  const int g = h >> 2;
  const int q0 = ((int)gridDim.y - 1 - (int)blockIdx.y) * 128;  // longest first

  const unsigned short* qhead = qb + (size_t)bh * SEQ * 128;
  const unsigned short* khead = kb + (size_t)(b * NHK + g) * SEQ * 128;
  const unsigned short* vthead = vtb + (size_t)(b * NHK + g) * 128 * SEQ;

  // ---- Q fragments straight from global (rows rb*64 + wave*16 + m15).
  short8 qf[2][4];
#pragma unroll
  for (int rb = 0; rb < 2; ++rb) {
    const unsigned short* qp = qhead + (size_t)(q0 + rb * 64 + wave * 16 + m15) * 128 + quad * 8;
#pragma unroll
    for (int ks = 0; ks < 4; ++ks) qf[rb][ks] = *(const short8*)(qp + ks * 32);
  }

  floatx4 acc_o[2][8];
#pragma unroll
  for (int rb = 0; rb < 2; ++rb)
#pragma unroll
    for (int n = 0; n < 8; ++n) acc_o[rb][n] = (floatx4){0.f, 0.f, 0.f, 0.f};
  float l_lane[2][4] = {{0.f, 0.f, 0.f, 0.f}, {0.f, 0.f, 0.f, 0.f}};
  const float inv_scale = 1.0f / 16384.0f;

  // ================= main loop: both row-blocks active, j0 <= q0 ===========
  for (int j0 = 0; j0 <= q0; j0 += 64) {
    // stage K tile (64 x 128), chunk-XOR swizzle
#pragma unroll
    for (int t = 0; t < 4; ++t) {
      const int r = wave * 16 + t * 4 + (lane >> 4);
      const int cg = (lane & 15) ^ (r & 15);
      const unsigned short* src = khead + (size_t)(j0 + r) * 128 + cg * 8;
      __builtin_amdgcn_global_load_lds(
          (const __attribute__((address_space(1))) void*)src,
          (__attribute__((address_space(3))) void*)&Ks[(wave * 16 + t * 4) * 128], 16, 0, 0);
    }
    // stage Vt tile (128 dims x 64 keys)
#pragma unroll
    for (int t = 0; t < 4; ++t) {
      const int d = wave * 32 + t * 8 + (lane >> 3);
      const int cg = (lane & 7) ^ (d & 7);
      const unsigned short* src = vthead + (size_t)d * SEQ + j0 + cg * 8;
      __builtin_amdgcn_global_load_lds(
          (const __attribute__((address_space(1))) void*)src,
          (__attribute__((address_space(3))) void*)&Vs[(wave * 32 + t * 8) * 64], 16, 0, 0);
    }
    __syncthreads();

    // S = Q K^T  (bfrag shared across rb)
    floatx4 acc_s[2][4];
#pragma unroll
    for (int rb = 0; rb < 2; ++rb)
#pragma unroll
      for (int n = 0; n < 4; ++n) acc_s[rb][n] = (floatx4){0.f, 0.f, 0.f, 0.f};
#pragma unroll
    for (int ks = 0; ks < 4; ++ks) {
#pragma unroll
      for (int n = 0; n < 4; ++n) {
        const short8 bfrag = *(const short8*)&Ks[(n * 16 + m15) * 128 + (((ks * 4 + quad) ^ m15) * 8)];
        acc_s[0][n] = __builtin_amdgcn_mfma_f32_16x16x32_bf16(qf[0][ks], bfrag, acc_s[0][n], 0, 0, 0);
        acc_s[1][n] = __builtin_amdgcn_mfma_f32_16x16x32_bf16(qf[1][ks], bfrag, acc_s[1][n], 0, 0, 0);
      }
    }

    // p = exp(s/16384); diagonal mask applies to rb=0 only when j0==q0
    // (rb=1 rows >= q0+64 > all cols of this tile).
    if (j0 == q0) {
      const int row_g = wave * 16 + quad * 4;
#pragma unroll
      for (int n = 0; n < 4; ++n) {
        const int col = n * 16 + m15;
#pragma unroll
        for (int rg = 0; rg < 4; ++rg) {
          float p = (col > row_g + rg) ? 0.0f : __expf(acc_s[0][n][rg] * inv_scale);
          l_lane[0][rg] += p;
          Ps[(wave * 16 + quad * 4 + rg) * 72 + n * 16 + m15] = f2bf(p);
          const float p1 = __expf(acc_s[1][n][rg] * inv_scale);
          l_lane[1][rg] += p1;
          Ps[(64 + wave * 16 + quad * 4 + rg) * 72 + n * 16 + m15] = f2bf(p1);
        }
      }
    } else {
#pragma unroll
      for (int n = 0; n < 4; ++n) {
#pragma unroll
        for (int rg = 0; rg < 4; ++rg) {
          const float p0 = __expf(acc_s[0][n][rg] * inv_scale);
          l_lane[0][rg] += p0;
          Ps[(wave * 16 + quad * 4 + rg) * 72 + n * 16 + m15] = f2bf(p0);
          const float p1 = __expf(acc_s[1][n][rg] * inv_scale);
          l_lane[1][rg] += p1;
          Ps[(64 + wave * 16 + quad * 4 + rg) * 72 + n * 16 + m15] = f2bf(p1);
        }
      }
    }

    // O += P V  (bfrag shared across rb; Ps rows wave-private)
#pragma unroll
    for (int kk = 0; kk < 2; ++kk) {
      const short8 a0 = *(const short8*)&Ps[(wave * 16 + m15) * 72 + kk * 32 + quad * 8];
      const short8 a1 = *(const short8*)&Ps[(64 + wave * 16 + m15) * 72 + kk * 32 + quad * 8];
#pragma unroll
      for (int n = 0; n < 8; ++n) {
        const short8 bfrag = *(const short8*)&Vs[(n * 16 + m15) * 64 + (((kk * 4 + quad) ^ (m15 & 7)) * 8)];
        acc_o[0][n] = __builtin_amdgcn_mfma_f32_16x16x32_bf16(a0, bfrag, acc_o[0][n], 0, 0, 0);
        acc_o[1][n] = __builtin_amdgcn_mfma_f32_16x16x32_bf16(a1, bfrag, acc_o[1][n], 0, 0, 0);
      }
    }
    __syncthreads();
  }

  // ============== peeled final half-tile: keys q0+64.., rb=1 only ==========
  {
    const int j0 = q0 + 64;
#pragma unroll
    for (int t = 0; t < 4; ++t) {
      const int r = wave * 16 + t * 4 + (lane >> 4);
      const int cg = (lane & 15) ^ (r & 15);
      const unsigned short* src = khead + (size_t)(j0 + r) * 128 + cg * 8;
      __builtin_amdgcn_global_load_lds(
          (const __attribute__((address_space(1))) void*)src,
          (__attribute__((address_space(3))) void*)&Ks[(wave * 16 + t * 4) * 128], 16, 0, 0);
    }
#pragma unroll
    for (int t = 0; t < 4; ++t) {
      const int d = wave * 32 + t * 8 + (lane >> 3);
      const int cg = (lane & 7) ^ (d & 7);
      const unsigned short* src = vthead + (size_t)d * SEQ + j0 + cg * 8;
      __builtin_amdgcn_global_load_lds(
          (const __attribute__((address_space(1))) void*)src,
          (__attribute__((address_space(3))) void*)&Vs[(wave * 32 + t * 8) * 64], 16, 0, 0);
    }
    __syncthreads();

    floatx4 acc_s[4];
#pragma unroll
    for (int n = 0; n < 4; ++n) acc_s[n] = (floatx4){0.f, 0.f, 0.f, 0.f};
#pragma unroll
    for (int ks = 0; ks < 4; ++ks) {
#pragma unroll
      for (int n = 0; n < 4; ++n) {
        const short8 bfrag = *(const short8*)&Ks[(n * 16 + m15) * 128 + (((ks * 4 + quad) ^ m15) * 8)];
        acc_s[n] = __builtin_amdgcn_mfma_f32_16x16x32_bf16(qf[1][ks], bfrag, acc_s[n], 0, 0, 0);
      }
    }
    const int row_g = wave * 16 + quad * 4;           // rb=1 rows, rel. to j0
#pragma unroll
    for (int n = 0; n < 4; ++n) {
      const int col = n * 16 + m15;
#pragma unroll
      for (int rg = 0; rg < 4; ++rg) {
        float p = (col > row_g + rg) ? 0.0f : __expf(acc_s[n][rg] * inv_scale);
        l_lane[1][rg] += p;
        Ps[(64 + wave * 16 + quad * 4 + rg) * 72 + n * 16 + m15] = f2bf(p);
      }
    }
#pragma unroll
    for (int kk = 0; kk < 2; ++kk) {
      const short8 a1 = *(const short8*)&Ps[(64 + wave * 16 + m15) * 72 + kk * 32 + quad * 8];
#pragma unroll
      for (int n = 0; n < 8; ++n) {
        const short8 bfrag = *(const short8*)&Vs[(n * 16 + m15) * 64 + (((kk * 4 + quad) ^ (m15 & 7)) * 8)];
        acc_o[1][n] = __builtin_amdgcn_mfma_f32_16x16x32_bf16(a1, bfrag, acc_o[1][n], 0, 0, 0);
      }
    }
  }

  // ---- final l reduction + epilogue (both row-blocks).
#pragma unroll
  for (int rb = 0; rb < 2; ++rb) {
#pragma unroll
    for (int rg = 0; rg < 4; ++rg) {
      float l = l_lane[rb][rg];
      l += __shfl_xor(l, 1);
      l += __shfl_xor(l, 2);
      l += __shfl_xor(l, 4);
      l += __shfl_xor(l, 8);
      const float invl = 1.0f / l;
      const size_t row = (size_t)(b * SEQ + q0 + rb * 64 + wave * 16 + quad * 4 + rg);
#pragma unroll
      for (int n = 0; n < 8; ++n)
        o[row * DMODEL + h * 128 + n * 16 + m15] = f2bf(acc_o[rb][n][rg] * invl);
    }
  }
}

// ---------------------------------------------------------------------------
extern "C" void kernel_launch(void* const* d_in, const int* in_sizes, int n_in,
                              void* d_out, int out_size, void* d_ws, size_t ws_size,
                              hipStream_t stream) {
  const float* x       = (const float*)d_in[0];
  const float* Wq      = (const float*)d_in[1];
  const float* Wk      = (const float*)d_in[2];
  const float* Wv      = (const float*)d_in[3];
  const float* Wo      = (const float*)d_in[4];
  const float* q_scale = (const float*)d_in[5];
  const float* k_scale = (const float*)d_in[6];
  const float* cosb    = (const float*)d_in[7];
  const float* sinb    = (const float*)d_in[8];
  float* out = (float*)d_out;

  // Workspace overlays (peak 83.89 MB = R1's proven footprint):
  char* w = (char*)d_ws;
  unsigned short* x_bf   = (unsigned short*)w;                // [0, 16.78M)
  float* qkv             = (float*)(w + 16777216);            // [16.78M, 67.11M)  [4096][3072]
  unsigned short* wqkv_t = (unsigned short*)(w + 67108864);   // [67.11M, 79.69M)  [3072][2048]
  // overlays (regions dead when these go live):
  unsigned short* q_bf    = (unsigned short*)(w + 67108864);  // over wqkv_t (16.78M, ends 83.89M)
  unsigned short* k_bf    = (unsigned short*)w;               // over x_bf (4.19M)
  unsigned short* vt      = (unsigned short*)(w + 4194304);   // over x_bf (4.19M)
  unsigned short* attn_bf = (unsigned short*)(w + 16777216);  // over dead qkv (16.78M)
  unsigned short* wo_t    = (unsigned short*)(w + 33554432);  // over dead qkv (8.39M)

  // Pre-pass: cast x; transpose Wq|Wk|Wv into one concatenated B^T.
  cast_bf16<<<(4096 * 2048 / 4) / 256, 256, 0, stream>>>(x, x_bf);
  transpose_cast<<<dim3(2048 / 32, 2048 / 32), dim3(32, 8), 0, stream>>>(Wq, wqkv_t, 2048, 2048);
  transpose_cast<<<dim3(512 / 32, 2048 / 32), dim3(32, 8), 0, stream>>>(Wk, wqkv_t + (size_t)2048 * 2048, 2048, 512);
  transpose_cast<<<dim3(512 / 32, 2048 / 32), dim3(32, 8), 0, stream>>>(Wv, wqkv_t + (size_t)2560 * 2048, 2048, 512);

  // Fused QKV projection: [4096][2048] @ [2048][3072] -> [4096][3072].
  gemm_bf16<<<dim3(3072 / 128, 4096 / 128), 256, 0, stream>>>(x_bf, wqkv_t, qkv, 4096, 3072, 2048);

  // RMSNorm + RoPE -> bf16 head-major; V -> bf16 transposed.
  rmsnorm_rope<<<dim3(4096, NHQ / 4), dim3(64, 4), 0, stream>>>(qkv, q_bf, 3072, 0, NHQ, q_scale, cosb, sinb);
  rmsnorm_rope<<<dim3(4096, NHK / 4), dim3(64, 4), 0, stream>>>(qkv, k_bf, 3072, 2048, NHK, k_scale, cosb, sinb);
  transpose_v<<<dim3(SEQ / 32, 128 / 32, 2 * NHK), dim3(32, 8), 0, stream>>>(qkv, vt);

  // Wo transpose (over dead qkv), attention, output projection.
  transpose_cast<<<dim3(2048 / 32, 2048 / 32), dim3(32, 8), 0, stream>>>(Wo, wo_t, 2048, 2048);
  attn_mfma<<<dim3(2 * NHQ, SEQ / 128), 256, 0, stream>>>(q_bf, k_bf, vt, attn_bf);
  gemm_bf16<<<dim3(2048 / 128, 4096 / 128), 256, 0, stream>>>(attn_bf, wo_t, out, 4096, 2048, 2048);
}

// Round 6
// 341.778 us; speedup vs baseline: 1.2425x; 1.2425x over previous
//
#include <hip/hip_runtime.h>
#include <math.h>

// Problem constants (fixed by reference):
// B=2, L=2048, D=2048, H=16, G=4, HD=128, EPS=1e-6, scale = 1/HD^2 = 1/16384
#define SEQ 2048
#define DMODEL 2048
#define NHQ 16
#define NHK 4

typedef __attribute__((ext_vector_type(8))) short short8;
typedef __attribute__((ext_vector_type(4))) float floatx4;

__device__ __forceinline__ unsigned short f2bf(float f) {
  unsigned int u = __builtin_bit_cast(unsigned int, f);
  u += 0x7fffu + ((u >> 16) & 1u);   // round-to-nearest-even
  return (unsigned short)(u >> 16);
}
__device__ __forceinline__ float bf2f(unsigned short s) {
  unsigned int u = ((unsigned int)s) << 16;
  return __builtin_bit_cast(float, u);
}

// ---------------------------------------------------------------------------
// cast fp32 -> bf16, 4 elements/thread.
// ---------------------------------------------------------------------------
__global__ __launch_bounds__(256) void cast_bf16(const float* __restrict__ in,
                                                 unsigned short* __restrict__ out) {
  const size_t i = ((size_t)blockIdx.x * 256 + threadIdx.x) * 4;
  const float4 v = *(const float4*)(in + i);
  ushort4 w;
  w.x = f2bf(v.x); w.y = f2bf(v.y); w.z = f2bf(v.z); w.w = f2bf(v.w);
  *(ushort4*)(out + i) = w;
}

// ---------------------------------------------------------------------------
// transpose + cast: in fp32 [R][C] -> out bf16 [C][R]. 32x32 LDS tile.
// ---------------------------------------------------------------------------
__global__ __launch_bounds__(256) void transpose_cast(const float* __restrict__ in,
                                                      unsigned short* __restrict__ out,
                                                      int R, int C) {
  __shared__ float tile[32][33];
  const int tx = threadIdx.x, ty = threadIdx.y;
  const int c0 = blockIdx.x * 32, r0 = blockIdx.y * 32;
#pragma unroll
  for (int j = 0; j < 4; ++j)
    tile[ty + j * 8][tx] = in[(size_t)(r0 + ty + j * 8) * C + c0 + tx];
  __syncthreads();
#pragma unroll
  for (int j = 0; j < 4; ++j)
    out[(size_t)(c0 + ty + j * 8) * R + r0 + tx] = f2bf(tile[tx][ty + j * 8]);
}

// ---------------------------------------------------------------------------
// V transpose from bf16 qkv buffer: qkv bf16 [b*L][3072] (V at 2560+g*128+d)
// -> vt bf16 [(b*G+g)][128][L]. block (32,8), grid (L/32, 128/32, B*G).
// ---------------------------------------------------------------------------
__global__ __launch_bounds__(256) void transpose_v(const unsigned short* __restrict__ in,
                                                   unsigned short* __restrict__ out) {
  __shared__ unsigned short tile[32][34];
  const int tx = threadIdx.x, ty = threadIdx.y;
  const int l0 = blockIdx.x * 32, d0 = blockIdx.y * 32;
  const int bg = blockIdx.z;                 // b*4+g
  const int b = bg >> 2, g = bg & 3;
#pragma unroll
  for (int j = 0; j < 4; ++j)
    tile[ty + j * 8][tx] = in[(size_t)(b * SEQ + l0 + ty + j * 8) * 3072 + 2560 + g * 128 + d0 + tx];
  __syncthreads();
#pragma unroll
  for (int j = 0; j < 4; ++j)
    out[((size_t)bg * 128 + d0 + ty + j * 8) * SEQ + l0 + tx] = tile[tx][ty + j * 8];
}

// ---------------------------------------------------------------------------
// bf16 MFMA GEMM (m97 structure): C = A @ B, fp32 or bf16 out.
// A row-major bf16 [M][K], Bt = B^T row-major bf16 [N][K].
// ---------------------------------------------------------------------------
template <typename OutT>
__global__ __launch_bounds__(256) void gemm_bf16(const unsigned short* __restrict__ A,
                                                 const unsigned short* __restrict__ Bt,
                                                 OutT* __restrict__ C,
                                                 int M, int N, int K) {
  __shared__ unsigned short As[128 * 32];
  __shared__ unsigned short Bs[128 * 32];
  const int tid = threadIdx.x;
  const int wave = tid >> 6;
  const int lane = tid & 63;
  const int bm = blockIdx.y * 128;
  const int bn = blockIdx.x * 128;
  const int wr = wave >> 1;
  const int wc = wave & 1;
  const int m15 = lane & 15;
  const int quad = lane >> 4;

  floatx4 acc[4][4];
#pragma unroll
  for (int i = 0; i < 4; ++i)
#pragma unroll
    for (int j = 0; j < 4; ++j) acc[i][j] = (floatx4){0.f, 0.f, 0.f, 0.f};

  const int srow = lane >> 2;
  const int scol = (lane & 3) * 8;

  for (int k0 = 0; k0 < K; k0 += 32) {
#pragma unroll
    for (int it = 0; it < 2; ++it) {
      const int rowa = wave * 32 + it * 16;
      const unsigned short* ga = A + (size_t)(bm + rowa + srow) * K + k0 + scol;
      const unsigned short* gb = Bt + (size_t)(bn + rowa + srow) * K + k0 + scol;
      __builtin_amdgcn_global_load_lds(
          (const __attribute__((address_space(1))) void*)ga,
          (__attribute__((address_space(3))) void*)&As[rowa * 32], 16, 0, 0);
      __builtin_amdgcn_global_load_lds(
          (const __attribute__((address_space(1))) void*)gb,
          (__attribute__((address_space(3))) void*)&Bs[rowa * 32], 16, 0, 0);
    }
    __syncthreads();

    short8 af[4], bfr[4];
    const unsigned short* pa = &As[(wr * 64 + m15) * 32 + quad * 8];
    const unsigned short* pb = &Bs[(wc * 64 + m15) * 32 + quad * 8];
#pragma unroll
    for (int i = 0; i < 4; ++i) af[i] = *(const short8*)(pa + i * 16 * 32);
#pragma unroll
    for (int j = 0; j < 4; ++j) bfr[j] = *(const short8*)(pb + j * 16 * 32);
#pragma unroll
    for (int i = 0; i < 4; ++i)
#pragma unroll
      for (int j = 0; j < 4; ++j)
        acc[i][j] = __builtin_amdgcn_mfma_f32_16x16x32_bf16(af[i], bfr[j], acc[i][j], 0, 0, 0);
    __syncthreads();
  }

#pragma unroll
  for (int i = 0; i < 4; ++i)
#pragma unroll
    for (int j = 0; j < 4; ++j) {
      const int col = bn + wc * 64 + j * 16 + m15;
#pragma unroll
      for (int reg = 0; reg < 4; ++reg) {
        const int row = bm + wr * 64 + i * 16 + quad * 4 + reg;
        if constexpr (sizeof(OutT) == 2)
          C[(size_t)row * N + col] = f2bf(acc[i][j][reg]);
        else
          C[(size_t)row * N + col] = acc[i][j][reg];
      }
    }
}

// ---------------------------------------------------------------------------
// Fused RMSNorm + RoPE for Q and K in one launch.
// qkv bf16 [b*L][3072]: Q at head*128 (heads 0..15), K at 2048+(head-16)*128.
// out q_bf [(b*16+h)][l][128], k_bf [(b*4+g)][l][128]. grid (4096, 5), block (64,4).
// ---------------------------------------------------------------------------
__global__ __launch_bounds__(256) void rmsnorm_rope_qk(const unsigned short* __restrict__ qkv,
                                                       unsigned short* __restrict__ qout,
                                                       unsigned short* __restrict__ kout,
                                                       const float* __restrict__ q_scale,
                                                       const float* __restrict__ k_scale,
                                                       const float* __restrict__ cosb,
                                                       const float* __restrict__ sinb) {
  const int t = threadIdx.x;                       // 0..63
  const int head = blockIdx.y * 4 + threadIdx.y;   // 0..19
  const int row = blockIdx.x;                      // 0..B*L-1
  const int b = row >> 11;
  const int l = row & (SEQ - 1);
  const bool is_q = head < NHQ;
  const int colOff = is_q ? head * 128 : 2048 + (head - NHQ) * 128;
  const float* scale = is_q ? q_scale : k_scale;
  unsigned short* dst = is_q
      ? qout + ((size_t)(b * NHQ + head) * SEQ + l) * 128
      : kout + ((size_t)(b * NHK + (head - NHQ)) * SEQ + l) * 128;

  const unsigned short* base = qkv + (size_t)row * 3072 + colOff;
  const float v0 = bf2f(base[t]);
  const float v1 = bf2f(base[t + 64]);
  float ss = v0 * v0 + v1 * v1;
#pragma unroll
  for (int m = 1; m < 64; m <<= 1) ss += __shfl_xor(ss, m);
  const float r = rsqrtf(ss * (1.0f / 128.0f) + 1e-6f);
  const float a0 = v0 * r * scale[t];
  const float a1 = v1 * r * scale[t + 64];
  const float c0 = cosb[(size_t)l * 128 + t];
  const float s0 = sinb[(size_t)l * 128 + t];
  const float c1 = cosb[(size_t)l * 128 + t + 64];
  const float s1 = sinb[(size_t)l * 128 + t + 64];
  dst[t]      = f2bf(a0 * c0 - a1 * s0);
  dst[t + 64] = f2bf(a1 * c1 + a0 * s1);
}

// ---------------------------------------------------------------------------
// MFMA flash attention (causal GQA), no-max softmax (R4 version — known-good).
// |s| = |q.k|/16384 <= 128/16384 by Cauchy-Schwarz (rms-normed q,k, unit
// scales, norm-preserving RoPE) -> exp(s) can't overflow; no running max.
// Grid (B*H, L/64) reversed-y, 256 threads = 4 waves; BM=64 (16 rows/wave).
// Q frags in registers; LDS: Ks 16K + Vs 16K + Ps 9K = 42 KB -> 3 blocks/CU.
// NOTE (R5 lesson): doubling to BM=128 spills accumulators to scratch
// (WRITE_SIZE 16->77 MB, 2.2x slower). Keep 8 acc + 4 qf per wave.
// ---------------------------------------------------------------------------
__global__ __launch_bounds__(256, 3) void attn_mfma(const unsigned short* __restrict__ qb,
                                                    const unsigned short* __restrict__ kb,
                                                    const unsigned short* __restrict__ vtb,
                                                    unsigned short* __restrict__ o) {
  __shared__ unsigned short Ks[64 * 128];
  __shared__ unsigned short Vs[128 * 64];
  __shared__ unsigned short Ps[64 * 72];

  const int tid = threadIdx.x;
  const int wave = tid >> 6;
  const int lane = tid & 63;
  const int m15 = lane & 15;
  const int quad = lane >> 4;
  const int bh = blockIdx.x;           // 0..31
  const int b = bh >> 4;
  const int h = bh & 15;
  const int g = h >> 2;
  const int q0 = ((int)gridDim.y - 1 - (int)blockIdx.y) * 64;  // longest first

  const unsigned short* qhead = qb + (size_t)bh * SEQ * 128;
  const unsigned short* khead = kb + (size_t)(b * NHK + g) * SEQ * 128;
  const unsigned short* vthead = vtb + (size_t)(b * NHK + g) * 128 * SEQ;

  // ---- Q fragments straight from global into registers (row = wave*16+m15).
  short8 qf[4];
  {
    const unsigned short* qp = qhead + (size_t)(q0 + wave * 16 + m15) * 128 + quad * 8;
#pragma unroll
    for (int ks = 0; ks < 4; ++ks) qf[ks] = *(const short8*)(qp + ks * 32);
  }

  floatx4 acc_o[8];
#pragma unroll
  for (int n = 0; n < 8; ++n) acc_o[n] = (floatx4){0.f, 0.f, 0.f, 0.f};
  float l_lane[4] = {0.f, 0.f, 0.f, 0.f};
  const float inv_scale = 1.0f / 16384.0f;

  for (int j0 = 0; j0 <= q0; j0 += 64) {
    // ---- stage K tile (64 x 128), chunk-XOR swizzle
#pragma unroll
    for (int t = 0; t < 4; ++t) {
      const int r = wave * 16 + t * 4 + (lane >> 4);
      const int cg = (lane & 15) ^ (r & 15);
      const unsigned short* src = khead + (size_t)(j0 + r) * 128 + cg * 8;
      __builtin_amdgcn_global_load_lds(
          (const __attribute__((address_space(1))) void*)src,
          (__attribute__((address_space(3))) void*)&Ks[(wave * 16 + t * 4) * 128], 16, 0, 0);
    }
    // ---- stage Vt tile (128 dims x 64 keys)
#pragma unroll
    for (int t = 0; t < 4; ++t) {
      const int d = wave * 32 + t * 8 + (lane >> 3);
      const int cg = (lane & 7) ^ (d & 7);
      const unsigned short* src = vthead + (size_t)d * SEQ + j0 + cg * 8;
      __builtin_amdgcn_global_load_lds(
          (const __attribute__((address_space(1))) void*)src,
          (__attribute__((address_space(3))) void*)&Vs[(wave * 32 + t * 8) * 64], 16, 0, 0);
    }
    __syncthreads();

    // ---- S = Q K^T
    floatx4 acc_s[4];
#pragma unroll
    for (int n = 0; n < 4; ++n) acc_s[n] = (floatx4){0.f, 0.f, 0.f, 0.f};
#pragma unroll
    for (int ks = 0; ks < 4; ++ks) {
#pragma unroll
      for (int n = 0; n < 4; ++n) {
        const short8 bfrag = *(const short8*)&Ks[(n * 16 + m15) * 128 + (((ks * 4 + quad) ^ m15) * 8)];
        acc_s[n] = __builtin_amdgcn_mfma_f32_16x16x32_bf16(qf[ks], bfrag, acc_s[n], 0, 0, 0);
      }
    }

    // ---- p = exp(s/16384); mask only on the diagonal tile.
    if (j0 == q0) {
      const int row_g = wave * 16 + quad * 4;        // + rg (relative to q0)
#pragma unroll
      for (int n = 0; n < 4; ++n) {
        const int col = n * 16 + m15;
#pragma unroll
        for (int rg = 0; rg < 4; ++rg) {
          float p = (col > row_g + rg) ? 0.0f : __expf(acc_s[n][rg] * inv_scale);
          l_lane[rg] += p;
          Ps[(wave * 16 + quad * 4 + rg) * 72 + n * 16 + m15] = f2bf(p);
        }
      }
    } else {
#pragma unroll
      for (int n = 0; n < 4; ++n) {
#pragma unroll
        for (int rg = 0; rg < 4; ++rg) {
          const float p = __expf(acc_s[n][rg] * inv_scale);
          l_lane[rg] += p;
          Ps[(wave * 16 + quad * 4 + rg) * 72 + n * 16 + m15] = f2bf(p);
        }
      }
    }

    // ---- O += P V
#pragma unroll
    for (int kk = 0; kk < 2; ++kk) {
      const short8 a = *(const short8*)&Ps[(wave * 16 + m15) * 72 + kk * 32 + quad * 8];
#pragma unroll
      for (int n = 0; n < 8; ++n) {
        const short8 bfrag = *(const short8*)&Vs[(n * 16 + m15) * 64 + (((kk * 4 + quad) ^ (m15 & 7)) * 8)];
        acc_o[n] = __builtin_amdgcn_mfma_f32_16x16x32_bf16(a, bfrag, acc_o[n], 0, 0, 0);
      }
    }
    __syncthreads();
  }

  // ---- final l reduction across the 16 m15 lanes, then epilogue.
#pragma unroll
  for (int rg = 0; rg < 4; ++rg) {
    float l = l_lane[rg];
    l += __shfl_xor(l, 1);
    l += __shfl_xor(l, 2);
    l += __shfl_xor(l, 4);
    l += __shfl_xor(l, 8);
    const float invl = 1.0f / l;
    const size_t row = (size_t)(b * SEQ + q0 + wave * 16 + quad * 4 + rg);
#pragma unroll
    for (int n = 0; n < 8; ++n)
      o[row * DMODEL + h * 128 + n * 16 + m15] = f2bf(acc_o[n][rg] * invl);
  }
}

// ---------------------------------------------------------------------------
extern "C" void kernel_launch(void* const* d_in, const int* in_sizes, int n_in,
                              void* d_out, int out_size, void* d_ws, size_t ws_size,
                              hipStream_t stream) {
  const float* x       = (const float*)d_in[0];
  const float* Wq      = (const float*)d_in[1];
  const float* Wk      = (const float*)d_in[2];
  const float* Wv      = (const float*)d_in[3];
  const float* Wo      = (const float*)d_in[4];
  const float* q_scale = (const float*)d_in[5];
  const float* k_scale = (const float*)d_in[6];
  const float* cosb    = (const float*)d_in[7];
  const float* sinb    = (const float*)d_in[8];
  float* out = (float*)d_out;

  // Workspace overlays (peak 71.3 MB; 83.9 MB proven available):
  char* w = (char*)d_ws;
  unsigned short* x_bf   = (unsigned short*)w;                // [0, 16.78M)
  unsigned short* qkv_bf = (unsigned short*)(w + 16777216);   // [16.78M, 41.94M)  [4096][3072] bf16
  unsigned short* wqkv_t = (unsigned short*)(w + 41943040);   // [41.94M, 54.53M)  [3072][2048]
  unsigned short* k_bf   = (unsigned short*)(w + 54525952);   // [54.53M, 58.72M)
  unsigned short* vt     = (unsigned short*)(w + 58720256);   // [58.72M, 62.91M)
  unsigned short* wo_t   = (unsigned short*)(w + 62914560);   // [62.91M, 71.30M)
  // overlays (regions dead when these go live):
  unsigned short* q_bf    = (unsigned short*)w;               // over x_bf (dead after QKV GEMM)
  unsigned short* attn_bf = (unsigned short*)(w + 16777216);  // over qkv_bf (dead after rmsnorm/transpose_v)

  // Pre-pass: cast x; transpose Wq|Wk|Wv (concatenated) and Wo.
  cast_bf16<<<(4096 * 2048 / 4) / 256, 256, 0, stream>>>(x, x_bf);
  transpose_cast<<<dim3(2048 / 32, 2048 / 32), dim3(32, 8), 0, stream>>>(Wq, wqkv_t, 2048, 2048);
  transpose_cast<<<dim3(512 / 32, 2048 / 32), dim3(32, 8), 0, stream>>>(Wk, wqkv_t + (size_t)2048 * 2048, 2048, 512);
  transpose_cast<<<dim3(512 / 32, 2048 / 32), dim3(32, 8), 0, stream>>>(Wv, wqkv_t + (size_t)2560 * 2048, 2048, 512);
  transpose_cast<<<dim3(2048 / 32, 2048 / 32), dim3(32, 8), 0, stream>>>(Wo, wo_t, 2048, 2048);

  // Fused QKV projection -> bf16 [4096][3072].
  gemm_bf16<unsigned short><<<dim3(3072 / 128, 4096 / 128), 256, 0, stream>>>(
      x_bf, wqkv_t, qkv_bf, 4096, 3072, 2048);

  // RMSNorm + RoPE for Q and K in one launch; V transpose.
  rmsnorm_rope_qk<<<dim3(4096, 5), dim3(64, 4), 0, stream>>>(qkv_bf, q_bf, k_bf,
                                                             q_scale, k_scale, cosb, sinb);
  transpose_v<<<dim3(SEQ / 32, 128 / 32, 2 * NHK), dim3(32, 8), 0, stream>>>(qkv_bf, vt);

  // Attention (BM=64, known-good), then output projection (fp32 out).
  attn_mfma<<<dim3(2 * NHQ, SEQ / 64), 256, 0, stream>>>(q_bf, k_bf, vt, attn_bf);
  gemm_bf16<float><<<dim3(2048 / 128, 4096 / 128), 256, 0, stream>>>(
      attn_bf, wo_t, out, 4096, 2048, 2048);
}

// Round 7
// 327.553 us; speedup vs baseline: 1.2965x; 1.0434x over previous
//
#include <hip/hip_runtime.h>
#include <math.h>

// Problem constants (fixed by reference):
// B=2, L=2048, D=2048, H=16, G=4, HD=128, EPS=1e-6, scale = 1/HD^2 = 1/16384
#define SEQ 2048
#define DMODEL 2048
#define NHQ 16
#define NHK 4

typedef __attribute__((ext_vector_type(8))) short short8;
typedef __attribute__((ext_vector_type(4))) float floatx4;

__device__ __forceinline__ unsigned short f2bf(float f) {
  unsigned int u = __builtin_bit_cast(unsigned int, f);
  u += 0x7fffu + ((u >> 16) & 1u);   // round-to-nearest-even
  return (unsigned short)(u >> 16);
}
__device__ __forceinline__ float bf2f(unsigned short s) {
  unsigned int u = ((unsigned int)s) << 16;
  return __builtin_bit_cast(float, u);
}

// ---------------------------------------------------------------------------
// cast fp32 -> bf16, 4 elements/thread.
// ---------------------------------------------------------------------------
__global__ __launch_bounds__(256) void cast_bf16(const float* __restrict__ in,
                                                 unsigned short* __restrict__ out) {
  const size_t i = ((size_t)blockIdx.x * 256 + threadIdx.x) * 4;
  const float4 v = *(const float4*)(in + i);
  ushort4 w;
  w.x = f2bf(v.x); w.y = f2bf(v.y); w.z = f2bf(v.z); w.w = f2bf(v.w);
  *(ushort4*)(out + i) = w;
}

// ---------------------------------------------------------------------------
// All 4 weight transposes in one launch. grid (64, 64, 3), block (32,8).
// z=0: Wq -> wqkv_t[0:2048];  z=1: Wo -> wo_t;
// z=2: x<16 -> Wk -> wqkv_t[2048:2560], x in [16,32) -> Wv -> wqkv_t[2560:3072].
// ---------------------------------------------------------------------------
__global__ __launch_bounds__(256) void transpose_weights(const float* __restrict__ Wq,
                                                         const float* __restrict__ Wk,
                                                         const float* __restrict__ Wv,
                                                         const float* __restrict__ Wo,
                                                         unsigned short* __restrict__ wqkv_t,
                                                         unsigned short* __restrict__ wo_t) {
  const int z = blockIdx.z;
  int bx = blockIdx.x;
  const float* in;
  unsigned short* out;
  int C;
  const int R = 2048;
  if (z == 0)      { in = Wq; out = wqkv_t;                         C = 2048; }
  else if (z == 1) { in = Wo; out = wo_t;                           C = 2048; }
  else {
    if (bx < 16)      { in = Wk; out = wqkv_t + (size_t)2048 * 2048; C = 512; }
    else if (bx < 32) { in = Wv; out = wqkv_t + (size_t)2560 * 2048; C = 512; bx -= 16; }
    else return;
  }
  __shared__ float tile[32][33];
  const int tx = threadIdx.x, ty = threadIdx.y;
  const int c0 = bx * 32, r0 = blockIdx.y * 32;
#pragma unroll
  for (int j = 0; j < 4; ++j)
    tile[ty + j * 8][tx] = in[(size_t)(r0 + ty + j * 8) * C + c0 + tx];
  __syncthreads();
#pragma unroll
  for (int j = 0; j < 4; ++j)
    out[(size_t)(c0 + ty + j * 8) * R + r0 + tx] = f2bf(tile[tx][ty + j * 8]);
}

// ---------------------------------------------------------------------------
// Fused QKV GEMM + RMSNorm + RoPE + V-transpose.
// C = x_bf[4096][2048] @ Wqkv[2048][3072]; each 128-col block tile is exactly
// one head: bx<16 -> Q head bx, 16..19 -> K head bx-16, 20..23 -> V head bx-20.
// K-loop = m97 structure. Epilogue: acc -> padded LDS tile (stride 129
// halfwords: both row-major and col-major lane sweeps are 2-way/free), then
//   Q/K: per-row 128-dim RMSNorm (64-lane shuffle) + RoPE -> head-major bf16
//   V:   transposed store -> vt[(b*4+g)][d][l]
// LDS: max(staging 16 KB, tile 33 KB) = 33 KB (aliased).
// ---------------------------------------------------------------------------
__global__ __launch_bounds__(256) void gemm_qkv_fused(const unsigned short* __restrict__ A,
                                                      const unsigned short* __restrict__ Bt,
                                                      unsigned short* __restrict__ qout,
                                                      unsigned short* __restrict__ kout,
                                                      unsigned short* __restrict__ vout,
                                                      const float* __restrict__ q_scale,
                                                      const float* __restrict__ k_scale,
                                                      const float* __restrict__ cosb,
                                                      const float* __restrict__ sinb) {
  __shared__ unsigned short smem[128 * 129];   // 33 KB; first 16 KB doubles as As|Bs
  unsigned short* As = smem;
  unsigned short* Bs = smem + 128 * 32;

  const int tid = threadIdx.x;
  const int wave = tid >> 6;
  const int lane = tid & 63;
  const int bm = blockIdx.y * 128;
  const int bx = blockIdx.x;            // head-block 0..23
  const int bn = bx * 128;
  const int wr = wave >> 1;
  const int wc = wave & 1;
  const int m15 = lane & 15;
  const int quad = lane >> 4;

  floatx4 acc[4][4];
#pragma unroll
  for (int i = 0; i < 4; ++i)
#pragma unroll
    for (int j = 0; j < 4; ++j) acc[i][j] = (floatx4){0.f, 0.f, 0.f, 0.f};

  const int srow = lane >> 2;
  const int scol = (lane & 3) * 8;

  for (int k0 = 0; k0 < 2048; k0 += 32) {
#pragma unroll
    for (int it = 0; it < 2; ++it) {
      const int rowa = wave * 32 + it * 16;
      const unsigned short* ga = A + (size_t)(bm + rowa + srow) * 2048 + k0 + scol;
      const unsigned short* gb = Bt + (size_t)(bn + rowa + srow) * 2048 + k0 + scol;
      __builtin_amdgcn_global_load_lds(
          (const __attribute__((address_space(1))) void*)ga,
          (__attribute__((address_space(3))) void*)&As[rowa * 32], 16, 0, 0);
      __builtin_amdgcn_global_load_lds(
          (const __attribute__((address_space(1))) void*)gb,
          (__attribute__((address_space(3))) void*)&Bs[rowa * 32], 16, 0, 0);
    }
    __syncthreads();

    short8 af[4], bfr[4];
    const unsigned short* pa = &As[(wr * 64 + m15) * 32 + quad * 8];
    const unsigned short* pb = &Bs[(wc * 64 + m15) * 32 + quad * 8];
#pragma unroll
    for (int i = 0; i < 4; ++i) af[i] = *(const short8*)(pa + i * 16 * 32);
#pragma unroll
    for (int j = 0; j < 4; ++j) bfr[j] = *(const short8*)(pb + j * 16 * 32);
#pragma unroll
    for (int i = 0; i < 4; ++i)
#pragma unroll
      for (int j = 0; j < 4; ++j)
        acc[i][j] = __builtin_amdgcn_mfma_f32_16x16x32_bf16(af[i], bfr[j], acc[i][j], 0, 0, 0);
    __syncthreads();
  }

  // ---- phase 1: acc -> padded bf16 LDS tile (stride 129 halfwords).
#pragma unroll
  for (int i = 0; i < 4; ++i)
#pragma unroll
    for (int j = 0; j < 4; ++j) {
      const int col = wc * 64 + j * 16 + m15;
#pragma unroll
      for (int reg = 0; reg < 4; ++reg) {
        const int row = wr * 64 + i * 16 + quad * 4 + reg;
        smem[row * 129 + col] = f2bf(acc[i][j][reg]);
      }
    }
  __syncthreads();

  // ---- phase 2: per-head epilogue.
  const int t = tid & 63;
  const int wv = tid >> 6;
  const int b = bm >> 11;                  // batch (bm multiple of 128)
  const int l_base = bm & (SEQ - 1);

  if (bx < 20) {
    // Q or K head: RMSNorm + RoPE, head-major output.
    const float* scale = (bx < NHQ) ? q_scale : k_scale;
    unsigned short* dstbase = (bx < NHQ)
        ? qout + ((size_t)(b * NHQ + bx) * SEQ + l_base) * 128
        : kout + ((size_t)(b * NHK + (bx - NHQ)) * SEQ + l_base) * 128;
    const float sc0 = scale[t];
    const float sc1 = scale[t + 64];
#pragma unroll 4
    for (int rr = 0; rr < 32; ++rr) {
      const int row = wv * 32 + rr;
      const float v0 = bf2f(smem[row * 129 + t]);
      const float v1 = bf2f(smem[row * 129 + t + 64]);
      float ss = v0 * v0 + v1 * v1;
#pragma unroll
      for (int m = 1; m < 64; m <<= 1) ss += __shfl_xor(ss, m);
      const float r = rsqrtf(ss * (1.0f / 128.0f) + 1e-6f);
      const int l = l_base + row;
      const float c0 = cosb[(size_t)l * 128 + t];
      const float s0 = sinb[(size_t)l * 128 + t];
      const float c1 = cosb[(size_t)l * 128 + t + 64];
      const float s1 = sinb[(size_t)l * 128 + t + 64];
      const float a0 = v0 * r * sc0;
      const float a1 = v1 * r * sc1;
      unsigned short* dst = dstbase + (size_t)row * 128;
      dst[t]      = f2bf(a0 * c0 - a1 * s0);
      dst[t + 64] = f2bf(a1 * c1 + a0 * s1);
    }
  } else {
    // V head: transposed store -> vt[(b*4+g)][d][l_base + t(/+64)].
    const int g = bx - 20;
    unsigned short* vbase = vout + (size_t)(b * NHK + g) * 128 * SEQ + l_base;
#pragma unroll 4
    for (int dd = 0; dd < 32; ++dd) {
      const int d = wv * 32 + dd;
      unsigned short* dst = vbase + (size_t)d * SEQ;
      dst[t]      = smem[t * 129 + d];
      dst[t + 64] = smem[(t + 64) * 129 + d];
    }
  }
}

// ---------------------------------------------------------------------------
// bf16 MFMA GEMM (m97 structure): C = A @ B, fp32 out (used for Wo).
// ---------------------------------------------------------------------------
__global__ __launch_bounds__(256) void gemm_bf16_f32(const unsigned short* __restrict__ A,
                                                     const unsigned short* __restrict__ Bt,
                                                     float* __restrict__ C,
                                                     int M, int N, int K) {
  __shared__ unsigned short As[128 * 32];
  __shared__ unsigned short Bs[128 * 32];
  const int tid = threadIdx.x;
  const int wave = tid >> 6;
  const int lane = tid & 63;
  const int bm = blockIdx.y * 128;
  const int bn = blockIdx.x * 128;
  const int wr = wave >> 1;
  const int wc = wave & 1;
  const int m15 = lane & 15;
  const int quad = lane >> 4;

  floatx4 acc[4][4];
#pragma unroll
  for (int i = 0; i < 4; ++i)
#pragma unroll
    for (int j = 0; j < 4; ++j) acc[i][j] = (floatx4){0.f, 0.f, 0.f, 0.f};

  const int srow = lane >> 2;
  const int scol = (lane & 3) * 8;

  for (int k0 = 0; k0 < K; k0 += 32) {
#pragma unroll
    for (int it = 0; it < 2; ++it) {
      const int rowa = wave * 32 + it * 16;
      const unsigned short* ga = A + (size_t)(bm + rowa + srow) * K + k0 + scol;
      const unsigned short* gb = Bt + (size_t)(bn + rowa + srow) * K + k0 + scol;
      __builtin_amdgcn_global_load_lds(
          (const __attribute__((address_space(1))) void*)ga,
          (__attribute__((address_space(3))) void*)&As[rowa * 32], 16, 0, 0);
      __builtin_amdgcn_global_load_lds(
          (const __attribute__((address_space(1))) void*)gb,
          (__attribute__((address_space(3))) void*)&Bs[rowa * 32], 16, 0, 0);
    }
    __syncthreads();

    short8 af[4], bfr[4];
    const unsigned short* pa = &As[(wr * 64 + m15) * 32 + quad * 8];
    const unsigned short* pb = &Bs[(wc * 64 + m15) * 32 + quad * 8];
#pragma unroll
    for (int i = 0; i < 4; ++i) af[i] = *(const short8*)(pa + i * 16 * 32);
#pragma unroll
    for (int j = 0; j < 4; ++j) bfr[j] = *(const short8*)(pb + j * 16 * 32);
#pragma unroll
    for (int i = 0; i < 4; ++i)
#pragma unroll
      for (int j = 0; j < 4; ++j)
        acc[i][j] = __builtin_amdgcn_mfma_f32_16x16x32_bf16(af[i], bfr[j], acc[i][j], 0, 0, 0);
    __syncthreads();
  }

#pragma unroll
  for (int i = 0; i < 4; ++i)
#pragma unroll
    for (int j = 0; j < 4; ++j) {
      const int col = bn + wc * 64 + j * 16 + m15;
#pragma unroll
      for (int reg = 0; reg < 4; ++reg) {
        const int row = bm + wr * 64 + i * 16 + quad * 4 + reg;
        C[(size_t)row * N + col] = acc[i][j][reg];
      }
    }
}

// ---------------------------------------------------------------------------
// MFMA flash attention (causal GQA), no-max softmax (known-good R4 kernel).
// |s| = |q.k|/16384 <= 128/16384 by Cauchy-Schwarz (rms-normed q,k, unit
// scales, norm-preserving RoPE) -> exp(s) can't overflow; no running max.
// Grid (B*H, L/64) reversed-y, 256 threads = 4 waves; BM=64 (16 rows/wave).
// NOTE (R5 lesson): BM=128 spills accumulators to scratch. Keep 8 acc/wave.
// ---------------------------------------------------------------------------
__global__ __launch_bounds__(256, 3) void attn_mfma(const unsigned short* __restrict__ qb,
                                                    const unsigned short* __restrict__ kb,
                                                    const unsigned short* __restrict__ vtb,
                                                    unsigned short* __restrict__ o) {
  __shared__ unsigned short Ks[64 * 128];
  __shared__ unsigned short Vs[128 * 64];
  __shared__ unsigned short Ps[64 * 72];

  const int tid = threadIdx.x;
  const int wave = tid >> 6;
  const int lane = tid & 63;
  const int m15 = lane & 15;
  const int quad = lane >> 4;
  const int bh = blockIdx.x;           // 0..31
  const int b = bh >> 4;
  const int h = bh & 15;
  const int g = h >> 2;
  const int q0 = ((int)gridDim.y - 1 - (int)blockIdx.y) * 64;  // longest first

  const unsigned short* qhead = qb + (size_t)bh * SEQ * 128;
  const unsigned short* khead = kb + (size_t)(b * NHK + g) * SEQ * 128;
  const unsigned short* vthead = vtb + (size_t)(b * NHK + g) * 128 * SEQ;

  short8 qf[4];
  {
    const unsigned short* qp = qhead + (size_t)(q0 + wave * 16 + m15) * 128 + quad * 8;
#pragma unroll
    for (int ks = 0; ks < 4; ++ks) qf[ks] = *(const short8*)(qp + ks * 32);
  }

  floatx4 acc_o[8];
#pragma unroll
  for (int n = 0; n < 8; ++n) acc_o[n] = (floatx4){0.f, 0.f, 0.f, 0.f};
  float l_lane[4] = {0.f, 0.f, 0.f, 0.f};
  const float inv_scale = 1.0f / 16384.0f;

  for (int j0 = 0; j0 <= q0; j0 += 64) {
#pragma unroll
    for (int t = 0; t < 4; ++t) {
      const int r = wave * 16 + t * 4 + (lane >> 4);
      const int cg = (lane & 15) ^ (r & 15);
      const unsigned short* src = khead + (size_t)(j0 + r) * 128 + cg * 8;
      __builtin_amdgcn_global_load_lds(
          (const __attribute__((address_space(1))) void*)src,
          (__attribute__((address_space(3))) void*)&Ks[(wave * 16 + t * 4) * 128], 16, 0, 0);
    }
#pragma unroll
    for (int t = 0; t < 4; ++t) {
      const int d = wave * 32 + t * 8 + (lane >> 3);
      const int cg = (lane & 7) ^ (d & 7);
      const unsigned short* src = vthead + (size_t)d * SEQ + j0 + cg * 8;
      __builtin_amdgcn_global_load_lds(
          (const __attribute__((address_space(1))) void*)src,
          (__attribute__((address_space(3))) void*)&Vs[(wave * 32 + t * 8) * 64], 16, 0, 0);
    }
    __syncthreads();

    floatx4 acc_s[4];
#pragma unroll
    for (int n = 0; n < 4; ++n) acc_s[n] = (floatx4){0.f, 0.f, 0.f, 0.f};
#pragma unroll
    for (int ks = 0; ks < 4; ++ks) {
#pragma unroll
      for (int n = 0; n < 4; ++n) {
        const short8 bfrag = *(const short8*)&Ks[(n * 16 + m15) * 128 + (((ks * 4 + quad) ^ m15) * 8)];
        acc_s[n] = __builtin_amdgcn_mfma_f32_16x16x32_bf16(qf[ks], bfrag, acc_s[n], 0, 0, 0);
      }
    }

    if (j0 == q0) {
      const int row_g = wave * 16 + quad * 4;
#pragma unroll
      for (int n = 0; n < 4; ++n) {
        const int col = n * 16 + m15;
#pragma unroll
        for (int rg = 0; rg < 4; ++rg) {
          float p = (col > row_g + rg) ? 0.0f : __expf(acc_s[n][rg] * inv_scale);
          l_lane[rg] += p;
          Ps[(wave * 16 + quad * 4 + rg) * 72 + n * 16 + m15] = f2bf(p);
        }
      }
    } else {
#pragma unroll
      for (int n = 0; n < 4; ++n) {
#pragma unroll
        for (int rg = 0; rg < 4; ++rg) {
          const float p = __expf(acc_s[n][rg] * inv_scale);
          l_lane[rg] += p;
          Ps[(wave * 16 + quad * 4 + rg) * 72 + n * 16 + m15] = f2bf(p);
        }
      }
    }

#pragma unroll
    for (int kk = 0; kk < 2; ++kk) {
      const short8 a = *(const short8*)&Ps[(wave * 16 + m15) * 72 + kk * 32 + quad * 8];
#pragma unroll
      for (int n = 0; n < 8; ++n) {
        const short8 bfrag = *(const short8*)&Vs[(n * 16 + m15) * 64 + (((kk * 4 + quad) ^ (m15 & 7)) * 8)];
        acc_o[n] = __builtin_amdgcn_mfma_f32_16x16x32_bf16(a, bfrag, acc_o[n], 0, 0, 0);
      }
    }
    __syncthreads();
  }

#pragma unroll
  for (int rg = 0; rg < 4; ++rg) {
    float l = l_lane[rg];
    l += __shfl_xor(l, 1);
    l += __shfl_xor(l, 2);
    l += __shfl_xor(l, 4);
    l += __shfl_xor(l, 8);
    const float invl = 1.0f / l;
    const size_t row = (size_t)(b * SEQ + q0 + wave * 16 + quad * 4 + rg);
#pragma unroll
    for (int n = 0; n < 8; ++n)
      o[row * DMODEL + h * 128 + n * 16 + m15] = f2bf(acc_o[n][rg] * invl);
  }
}

// ---------------------------------------------------------------------------
extern "C" void kernel_launch(void* const* d_in, const int* in_sizes, int n_in,
                              void* d_out, int out_size, void* d_ws, size_t ws_size,
                              hipStream_t stream) {
  const float* x       = (const float*)d_in[0];
  const float* Wq      = (const float*)d_in[1];
  const float* Wk      = (const float*)d_in[2];
  const float* Wv      = (const float*)d_in[3];
  const float* Wo      = (const float*)d_in[4];
  const float* q_scale = (const float*)d_in[5];
  const float* k_scale = (const float*)d_in[6];
  const float* cosb    = (const float*)d_in[7];
  const float* sinb    = (const float*)d_in[8];
  float* out = (float*)d_out;

  // Workspace (79.69 MB, no overlays; 83.9 MB proven available):
  char* w = (char*)d_ws;
  unsigned short* x_bf    = (unsigned short*)w;               // [0, 16.78M)
  unsigned short* wqkv_t  = (unsigned short*)(w + 16777216);  // [16.78M, 29.36M)
  unsigned short* q_bf    = (unsigned short*)(w + 29360128);  // [29.36M, 46.14M)
  unsigned short* k_bf    = (unsigned short*)(w + 46137344);  // [46.14M, 50.33M)
  unsigned short* vt      = (unsigned short*)(w + 50331648);  // [50.33M, 54.53M)
  unsigned short* wo_t    = (unsigned short*)(w + 54525952);  // [54.53M, 62.91M)
  unsigned short* attn_bf = (unsigned short*)(w + 62914560);  // [62.91M, 79.69M)

  // Pre-pass: cast x; all weight transposes in one launch.
  cast_bf16<<<(4096 * 2048 / 4) / 256, 256, 0, stream>>>(x, x_bf);
  transpose_weights<<<dim3(64, 64, 3), dim3(32, 8), 0, stream>>>(Wq, Wk, Wv, Wo, wqkv_t, wo_t);

  // Fused QKV projection + RMSNorm + RoPE + V-transpose.
  gemm_qkv_fused<<<dim3(24, 32), 256, 0, stream>>>(x_bf, wqkv_t, q_bf, k_bf, vt,
                                                   q_scale, k_scale, cosb, sinb);

  // Attention, then output projection.
  attn_mfma<<<dim3(2 * NHQ, SEQ / 64), 256, 0, stream>>>(q_bf, k_bf, vt, attn_bf);
  gemm_bf16_f32<<<dim3(2048 / 128, 4096 / 128), 256, 0, stream>>>(
      attn_bf, wo_t, out, 4096, 2048, 2048);
}